// Round 1
// baseline (447.034 us; speedup 1.0000x reference)
//
#include <hip/hip_runtime.h>
#include <stdint.h>

#define NN 8192
#define DIM 128
#define ALPHA 0.2f
#define MTILE 16
#define BTHREADS 512          // 8 waves, each owns a 16-col slice of the 128-dim output
#define BK 256                // k-chunk per LDS tile
#define NCHUNK (NN / BK)      // 32
#define WSTRIDE (BK + 8)      // +16B pad to spread LDS banks

typedef float f32x4 __attribute__((ext_vector_type(4)));
typedef short bf16x8 __attribute__((ext_vector_type(8)));

__device__ __forceinline__ float b2f(uint32_t u){
  uint32_t x = u << 16;
  float f;
  __builtin_memcpy(&f, &x, 4);
  return f;
}
__device__ __forceinline__ uint16_t f2b(float f){
  uint32_t x;
  __builtin_memcpy(&x, &f, 4);
  x += 0x7FFFu + ((x >> 16) & 1u);
  return (uint16_t)(x >> 16);
}

// Fused prep: one pass over nodes produces s1, s2 (fp32 dots with a) AND
// nodesT[n][k] = bf16(nodes[k][n]).  Grid: NN/32 blocks x 256 threads.
// Thread (r, t): row = 32*blk + r (r=tid>>3), dims [16t, 16t+16) (t=tid&7).
__global__ void __launch_bounds__(256)
prep_kernel(const float* __restrict__ nodes, const float* __restrict__ a,
            float* __restrict__ s1, float* __restrict__ s2,
            uint16_t* __restrict__ nodesT){
  __shared__ __align__(16) uint16_t tile[DIM][40];   // [n][r], stride 80B (16B-mult)

  const int r   = threadIdx.x >> 3;          // 0..31
  const int t   = threadIdx.x & 7;           // 0..7
  const int row = blockIdx.x * 32 + r;

  const float* np = nodes + (size_t)row * DIM + t * 16;
  float4 v0 = *(const float4*)(np);
  float4 v1 = *(const float4*)(np + 4);
  float4 v2 = *(const float4*)(np + 8);
  float4 v3 = *(const float4*)(np + 12);

  const float* a1p = a + t * 16;
  const float* a2p = a + DIM + t * 16;
  float4 b0 = *(const float4*)(a1p);
  float4 b1 = *(const float4*)(a1p + 4);
  float4 b2 = *(const float4*)(a1p + 8);
  float4 b3 = *(const float4*)(a1p + 12);
  float4 c0 = *(const float4*)(a2p);
  float4 c1 = *(const float4*)(a2p + 4);
  float4 c2 = *(const float4*)(a2p + 8);
  float4 c3 = *(const float4*)(a2p + 12);

  float p1 = v0.x*b0.x + v0.y*b0.y + v0.z*b0.z + v0.w*b0.w
           + v1.x*b1.x + v1.y*b1.y + v1.z*b1.z + v1.w*b1.w
           + v2.x*b2.x + v2.y*b2.y + v2.z*b2.z + v2.w*b2.w
           + v3.x*b3.x + v3.y*b3.y + v3.z*b3.z + v3.w*b3.w;
  float p2 = v0.x*c0.x + v0.y*c0.y + v0.z*c0.z + v0.w*c0.w
           + v1.x*c1.x + v1.y*c1.y + v1.z*c1.z + v1.w*c1.w
           + v2.x*c2.x + v2.y*c2.y + v2.z*c2.z + v2.w*c2.w
           + v3.x*c3.x + v3.y*c3.y + v3.z*c3.z + v3.w*c3.w;

  p1 += __shfl_down(p1, 4, 8);
  p1 += __shfl_down(p1, 2, 8);
  p1 += __shfl_down(p1, 1, 8);
  p2 += __shfl_down(p2, 4, 8);
  p2 += __shfl_down(p2, 2, 8);
  p2 += __shfl_down(p2, 1, 8);
  if (t == 0){ s1[row] = p1; s2[row] = p2; }

  // transpose stage: tile[dim][r] = bf16(node value)
  float vv[16] = {v0.x, v0.y, v0.z, v0.w, v1.x, v1.y, v1.z, v1.w,
                  v2.x, v2.y, v2.z, v2.w, v3.x, v3.y, v3.z, v3.w};
  #pragma unroll
  for (int j = 0; j < 16; j++)
    tile[t * 16 + j][r] = f2b(vv[j]);
  __syncthreads();

  // coalesced-ish write-out: thread u -> n = u>>1, k-half = u&1 (32B per thread)
  const int n  = threadIdx.x >> 1;
  const int hf = threadIdx.x & 1;
  uint16_t* op = nodesT + (size_t)n * NN + blockIdx.x * 32 + hf * 16;
  *(uint4*)(op)     = *(const uint4*)&tile[n][hf * 16];
  *(uint4*)(op + 8) = *(const uint4*)&tile[n][hf * 16 + 8];
}

// Fused GAT row-block: MTILE=16 rows, 512 blocks (2 blocks/CU for TLP).
// Each wave owns a full-K 16x16 output tile via mfma_f32_16x16x32_bf16:
// no k-half split, no accT combine, f32x4 accumulator.
__global__ void __launch_bounds__(BTHREADS, 4)   // cap VGPR<=128 -> 2 blocks/CU
attn_kernel(const float* __restrict__ dist,
            const uint16_t* __restrict__ nodesT,
            const float* __restrict__ s1,
            const float* __restrict__ s2,
            float* __restrict__ out){
  __shared__ __align__(16) uint16_t Wbuf[2][MTILE][WSTRIDE];   // 16.9 KB
  __shared__ float denT[MTILE];

  const int tid  = threadIdx.x;
  const int lane = tid & 63;
  const int wave = tid >> 6;
  const int i0   = blockIdx.x * MTILE;

  // ---- W-gen mapping: thread -> (row, 8 contiguous k's) ----
  const int wrow = tid >> 5;          // 0..15
  const int wr   = tid & 31;          // 0..31
  const float s1v = s1[i0 + wrow];
  const float* distRow = dist + (size_t)(i0 + wrow) * NN + wr * 8;

  // ---- MFMA mapping: wave -> n-cols [16*wave, 16*wave+16) ----
  const int c = lane & 15;            // A-row / B-col / D-col
  const int g = lane >> 4;            // k-group
  const uint16_t* bRow = nodesT + (size_t)(wave * 16 + c) * NN + g * 8;

  f32x4 acc = {0.f, 0.f, 0.f, 0.f};
  float den = 0.f;

  float4 pd0, pd1, ps0, ps1;

  auto load_chunk = [&](int s){
    const float* dpp = distRow + s * BK;
    const float* spp = s2 + s * BK + wr * 8;
    pd0 = *(const float4*)(dpp);
    pd1 = *(const float4*)(dpp + 4);
    ps0 = *(const float4*)(spp);
    ps1 = *(const float4*)(spp + 4);
  };

  auto gen_write = [&](int buf){
    float dv[8] = {pd0.x, pd0.y, pd0.z, pd0.w, pd1.x, pd1.y, pd1.z, pd1.w};
    float sv[8] = {ps0.x, ps0.y, ps0.z, ps0.w, ps1.x, ps1.y, ps1.z, ps1.w};
    union { bf16x8 v; uint16_t u[8]; } w0;
    #pragma unroll
    for (int j = 0; j < 8; j++){
      float x = s1v + sv[j];
      float e = fmaxf(x, ALPHA * x);
      float w = (dv[j] < 0.5f) ? __expf(e) : 0.f;
      uint16_t wq = f2b(w);
      w0.u[j] = wq;
      den += b2f((uint32_t)wq);     // denominator sees the SAME quantized W
    }
    *(bf16x8*)&Wbuf[buf][wrow][wr * 8] = w0.v;
  };

  // Prologue: chunk 0 into buf 0.
  load_chunk(0);
  gen_write(0);

  for (int s = 0; s < NCHUNK; s++){
    if (s + 1 < NCHUNK) load_chunk(s + 1);   // HBM prefetch (TLP across 2 blocks/CU)
    __syncthreads();
    const int buf = s & 1;
    const size_t kb = (size_t)s * BK;
    #pragma unroll
    for (int kk = 0; kk < 8; kk++){
      const int ko = kk * 32;
      bf16x8 av = *(const bf16x8*)&Wbuf[buf][c][ko + g * 8];
      bf16x8 bv = *(const bf16x8*)(bRow + kb + ko);
      acc = __builtin_amdgcn_mfma_f32_16x16x32_bf16(av, bv, acc, 0, 0, 0);
    }
    if (s + 1 < NCHUNK) gen_write((s + 1) & 1);
  }

  // ---- denominator: 32 threads per row -> width-32 shfl reduce ----
  den += __shfl_down(den, 16, 32);
  den += __shfl_down(den, 8, 32);
  den += __shfl_down(den, 4, 32);
  den += __shfl_down(den, 2, 32);
  den += __shfl_down(den, 1, 32);
  if (wr == 0) denT[wrow] = 1.0f / den;
  __syncthreads();

  // ---- epilogue: wave-local, no cross-wave combine ----
  #pragma unroll
  for (int r = 0; r < 4; r++){
    const int row = g * 4 + r;              // verified 16x16 C/D mapping
    out[(size_t)(i0 + row) * DIM + wave * 16 + c] = acc[r] * denT[row];
  }
}

extern "C" void kernel_launch(void* const* d_in, const int* in_sizes, int n_in,
                              void* d_out, int out_size, void* d_ws, size_t ws_size,
                              hipStream_t stream){
  const float* nodes = (const float*)d_in[0];
  const float* dist  = (const float*)d_in[1];
  const float* a     = (const float*)d_in[2];
  float* out = (float*)d_out;

  char* ws = (char*)d_ws;
  float*    s1     = (float*)ws;                     // 32 KB
  float*    s2     = (float*)(ws + (32 << 10));      // 32 KB
  uint16_t* nodesT = (uint16_t*)(ws + (64 << 10));   // 2 MB

  prep_kernel<<<NN / 32, 256, 0, stream>>>(nodes, a, s1, s2, nodesT);
  attn_kernel<<<NN / MTILE, BTHREADS, 0, stream>>>(dist, nodesT, s1, s2, out);
}